// Round 5
// baseline (338.281 us; speedup 1.0000x reference)
//
#include <hip/hip_runtime.h>

#define NROWS 8192
#define DDIM  1024           // elements per row (fp8: also bytes per row)
#define BM 128
#define BN 256
#define BKB 64               // K-bytes per pipeline tile (one K=64 MFMA slab)
#define NKT (DDIM / BKB)     // 16 K-tiles per col tile
#define NSTRIPES 8
#define CT_PER_STRIPE 4      // 8 stripes x 4 ct x 256 cols = 8192
#define TT (CT_PER_STRIPE * NKT)   // 64 pipeline tiles per block
#define MARGIN_F 0.05f
#define FP8_SCALE 8.0f       // power of 2; sims are scaled by 64 in mining space

typedef __attribute__((ext_vector_type(8)))  int   int8v;
typedef __attribute__((ext_vector_type(4)))  int   int4v;
typedef __attribute__((ext_vector_type(16))) float floatx16;

__device__ __forceinline__ void g2lds16(const void* g, void* l) {
  __builtin_amdgcn_global_load_lds(
      (const __attribute__((address_space(1))) void*)g,
      (__attribute__((address_space(3))) void*)l, 16, 0, 0);
}

#define MEMFENCE() asm volatile("" ::: "memory")
#define SBAR()  do { MEMFENCE(); __builtin_amdgcn_s_barrier(); MEMFENCE(); } while (0)
#define LGKM0() do { asm volatile("s_waitcnt lgkmcnt(0)" ::: "memory"); \
                     __builtin_amdgcn_sched_barrier(0); } while (0)
#define VMC(n)  asm volatile("s_waitcnt vmcnt(" #n ")" ::: "memory")

// prep: 2048 blocks x 256 threads; wave w handles row 4*blockIdx + w.
// Exact fp32 pos_sim, fp32 -> fp8(e4m3, x8) quantize, zero keys + out.
__global__ void prep_kernel(const float* __restrict__ x, const float* __restrict__ y,
                            unsigned int* __restrict__ xq, unsigned int* __restrict__ yq,
                            float* __restrict__ pos, unsigned int* __restrict__ keys,
                            float* __restrict__ out) {
  const int t = threadIdx.x;
  const int lane = t & 63, wave = t >> 6;
  const int row = blockIdx.x * 4 + wave;
  const float4* xr = (const float4*)(x + (size_t)row * DDIM);
  const float4* yr = (const float4*)(y + (size_t)row * DDIM);
  unsigned int* xqr = xq + (size_t)row * 256;
  unsigned int* yqr = yq + (size_t)row * 256;
  float s = 0.f;
#pragma unroll
  for (int u = 0; u < 4; ++u) {
    const float4 a = xr[u * 64 + lane];
    const float4 b = yr[u * 64 + lane];
    s += a.x * b.x + a.y * b.y + a.z * b.z + a.w * b.w;
    int pa = __builtin_amdgcn_cvt_pk_fp8_f32(a.x * FP8_SCALE, a.y * FP8_SCALE, 0, false);
    pa     = __builtin_amdgcn_cvt_pk_fp8_f32(a.z * FP8_SCALE, a.w * FP8_SCALE, pa, true);
    int pb = __builtin_amdgcn_cvt_pk_fp8_f32(b.x * FP8_SCALE, b.y * FP8_SCALE, 0, false);
    pb     = __builtin_amdgcn_cvt_pk_fp8_f32(b.z * FP8_SCALE, b.w * FP8_SCALE, pb, true);
    xqr[u * 64 + lane] = (unsigned int)pa;
    yqr[u * 64 + lane] = (unsigned int)pb;
  }
  for (int m = 32; m; m >>= 1) s += __shfl_down(s, m, 64);
  if (lane == 0) { pos[row] = s; keys[row] = 0u; }
  if (blockIdx.x == 0 && t == 0) out[0] = 0.f;
}

// R13: depth-2 counted-vmcnt pipeline (T3-lite+T4+T5) on the R8/R9-proven
// geometry. Post-mortems: R8's 123us is ~serial {stage 23us | lds 31us |
// mfma 29us} (m233's 2-phase tax); R9's prefetch failed because __syncthreads
// drains vmcnt(0) -> waits the just-issued stage; R10-R12 raised traffic or
// phases and all regressed. Fix here: raw s_barrier (no drain) + vmcnt(6)
// mid-loop (stage(g+1) done, stage(g+2) stays in flight) -> staging overlaps
// MFMA+ds_read; the two barrier-independent blocks/CU anti-phase on the LDS
// port; setprio(1) arbitrates for the MFMA-ing wave (role-split now exists).
// Per tile g: reads buf[g&1]; after the read-retire barrier, stage(g+2)
// overwrites buf[g&1] asynchronously.
// Geometry (register-proven, VGPR 128 no spill): 4 waves, wave tile 64x128,
// acc[2][4] AGPR, BKB=64 with R9's verified swizzle: chunk c of LDS row r at
// c^((r>>1)&3); ds_read pair at fragOff, ^16 for second chunk; staging swizzle
// carried by per-lane global source (sw = (t&3)^((t>>3)&3), i-independent).
// Epilogue: per-ct VALU key fold placed before the vmcnt (hides stage wait);
// one butterfly + atomicMax per row at kernel end.
__global__ __launch_bounds__(256, 2) void mine_kernel(
    const unsigned char* __restrict__ xq, const unsigned char* __restrict__ yq,
    const float* __restrict__ pos, unsigned int* __restrict__ keys) {
  __shared__ unsigned char As[2 * BM * BKB];  // 16 KB (2 x 8 KB)
  __shared__ unsigned char Bs[2 * BN * BKB];  // 32 KB (2 x 16 KB)
  __shared__ float pos_s[BM];

  const int t = threadIdx.x;
  const int rowBase = blockIdx.x * BM;
  const int stripe  = blockIdx.y;
  if (t < BM) pos_s[t] = pos[rowBase + t] * (FP8_SCALE * FP8_SCALE);

  const int lane = t & 63;
  const int wave = t >> 6;
  const int wr = wave >> 1, wc = wave & 1;   // wave tile 64 rows x 128 cols
  const int r31 = lane & 31, kh = lane >> 5;

  // ds_read side (R9-verified): fragment pair at fragOff / fragOff^16.
  const int fragOff = ((2 * kh) ^ ((r31 >> 1) & 3)) << 4;
  const int offA0 = (64 * wr + r31) * BKB + fragOff;    // + mi*32*BKB
  const int offB0 = (128 * wc + r31) * BKB + fragOff;   // + ni*32*BKB

  // Stage side (R9-verified): slot s = i*256+t; row r = i*64 + (t>>2);
  // chunk c = (t&3)^((t>>3)&3) (i-independent since i*64 = 0 mod 8-rows).
  const int stageOff = (t >> 2) * DDIM + (((t & 3) ^ ((t >> 3) & 3)) << 4);
  const unsigned char* aBase = xq + (size_t)rowBase * DDIM + stageOff;
  const unsigned char* bBase = yq + (size_t)(stripe * (BN * CT_PER_STRIPE)) * DDIM + stageOff;
  const int ldsDst = (wave * 64) * 16;   // + lane*16 added by HW

  // Stage tile j into buffer j&1: A 2 issues + B 4 issues per thread (6 vmem).
#define STAGE(j) do {                                                          \
    const int k0_ = ((j) & (NKT - 1)) * BKB;                                   \
    const size_t cOff_ = (size_t)((j) >> 4) * (BN * DDIM);                     \
    _Pragma("unroll")                                                          \
    for (int i_ = 0; i_ < 2; ++i_)                                             \
      g2lds16(aBase + (size_t)i_ * 64 * DDIM + k0_,                            \
              &As[((j) & 1) * (BM * BKB) + (i_ * 256) * 16 + ldsDst]);         \
    _Pragma("unroll")                                                          \
    for (int i_ = 0; i_ < 4; ++i_)                                             \
      g2lds16(bBase + cOff_ + (size_t)i_ * 64 * DDIM + k0_,                    \
              &Bs[((j) & 1) * (BN * BKB) + (i_ * 256) * 16 + ldsDst]);         \
  } while (0)

  unsigned int key[2][16];
#pragma unroll
  for (int mi = 0; mi < 2; ++mi)
#pragma unroll
    for (int reg = 0; reg < 16; ++reg) key[mi][reg] = 0u;

  floatx16 acc[2][4];
#pragma unroll
  for (int mi = 0; mi < 2; ++mi)
#pragma unroll
    for (int ni = 0; ni < 4; ++ni)
#pragma unroll
      for (int r = 0; r < 16; ++r) acc[mi][ni][r] = 0.f;

  // Prologue: fill both buffers; wait only the oldest 6 (tile 0).
  STAGE(0);
  STAGE(1);
  VMC(6);
  SBAR();

#pragma unroll 2
  for (int g = 0; g < TT; ++g) {
    const unsigned char* Ab = &As[(g & 1) * (BM * BKB)];
    const unsigned char* Bb = &Bs[(g & 1) * (BN * BKB)];

    // 1) fragment reads from buf[g&1]
    int8v af[2];
#pragma unroll
    for (int mi = 0; mi < 2; ++mi) {
      const int oA = offA0 + mi * 32 * BKB;
      int4v lo = *(const int4v*)&Ab[oA];
      int4v hi = *(const int4v*)&Ab[oA ^ 16];
      af[mi] = __builtin_shufflevector(lo, hi, 0, 1, 2, 3, 4, 5, 6, 7);
    }
    int8v bf[4];
#pragma unroll
    for (int ni = 0; ni < 4; ++ni) {
      const int oB = offB0 + ni * 32 * BKB;
      int4v lo = *(const int4v*)&Bb[oB];
      int4v hi = *(const int4v*)&Bb[oB ^ 16];
      bf[ni] = __builtin_shufflevector(lo, hi, 0, 1, 2, 3, 4, 5, 6, 7);
    }
    LGKM0();
    // 2) all waves' reads of buf[g&1] retired
    SBAR();
    // 3) async overwrite of buf[g&1] with tile g+2
    if (g + 2 < TT) STAGE(g + 2);
    // 4) MFMA cluster
    __builtin_amdgcn_s_setprio(1);
#pragma unroll
    for (int ni = 0; ni < 4; ++ni) {
      acc[0][ni] = __builtin_amdgcn_mfma_scale_f32_32x32x64_f8f6f4(
          af[0], bf[ni], acc[0][ni], 0, 0, 0, 0x7F7F7F7F, 0, 0x7F7F7F7F);
      acc[1][ni] = __builtin_amdgcn_mfma_scale_f32_32x32x64_f8f6f4(
          af[1], bf[ni], acc[1][ni], 0, 0, 0, 0x7F7F7F7F, 0, 0x7F7F7F7F);
    }
    __builtin_amdgcn_s_setprio(0);

    // ct-boundary key fold (VALU-only; hides the stage wait below).
    if ((g & (NKT - 1)) == (NKT - 1)) {
      const int colBase = stripe * (BN * CT_PER_STRIPE) + (g >> 4) * BN;
#pragma unroll
      for (int mi = 0; mi < 2; ++mi) {
#pragma unroll
        for (int reg = 0; reg < 16; ++reg) {
          const int row_l = 64 * wr + 32 * mi + (reg & 3) + 8 * (reg >> 2) + 4 * kh;
          const int row_g = rowBase + row_l;
          const float p = pos_s[row_l];
          unsigned int kk = key[mi][reg];
#pragma unroll
          for (int ni = 0; ni < 4; ++ni) {
            const int col = colBase + 128 * wc + 32 * ni + r31;
            const float v = acc[mi][ni][reg];
            const bool dead = (col == row_g) || (v > p);
            unsigned int u = __float_as_uint(v);
            u ^= (unsigned int)(((int)u) >> 31) | 0x80000000u;
            unsigned int kc = (u & 0xFFFFE000u) | (unsigned int)(8191 - col);
            kc = dead ? 0u : kc;
            kk = kk > kc ? kk : kc;
          }
          key[mi][reg] = kk;
          acc[mi][0][reg] = 0.f; acc[mi][1][reg] = 0.f;
          acc[mi][2][reg] = 0.f; acc[mi][3][reg] = 0.f;
        }
      }
    }

    // 5) counted guard: stage(g+1) must be complete before next iter's reads;
    //    stage(g+2) stays in flight. Never drain to 0 mid-loop.
    if (g < TT - 2)       { VMC(6); }
    else if (g == TT - 2) { VMC(0); }
    // 6) release buffers for next iteration
    if (g < TT - 1) SBAR();
  }

  // One butterfly + one atomic per owned row.
#pragma unroll
  for (int mi = 0; mi < 2; ++mi) {
#pragma unroll
    for (int reg = 0; reg < 16; ++reg) {
      unsigned int kk = key[mi][reg];
#pragma unroll
      for (int m = 1; m <= 16; m <<= 1) {
        unsigned int o = __shfl_xor(kk, m, 64);
        kk = kk > o ? kk : o;
      }
      if (r31 == 0) {
        const int row_l = 64 * wr + 32 * mi + (reg & 3) + 8 * (reg >> 2) + 4 * kh;
        atomicMax(&keys[rowBase + row_l], kk);
      }
    }
  }
#undef STAGE
}

// Exact fp32 recompute of neg_sim for the mined index + loss reduction.
// 1024 blocks -> ample wave parallelism for the latency-bound gather.
__global__ void final_kernel(const float* __restrict__ x, const float* __restrict__ y,
                             const float* __restrict__ pos,
                             const unsigned int* __restrict__ keys,
                             float* __restrict__ out) {
  const int t = threadIdx.x;
  const int lane = t & 63, wave = t >> 6;
  float accl = 0.f;
#pragma unroll
  for (int i = 0; i < 2; ++i) {
    const int row = blockIdx.x * 8 + i * 4 + wave;
    const unsigned int k = keys[row];
    const int j = (k == 0u) ? 0 : (8191 - (int)(k & 8191u));  // all-masked -> argmax 0
    const float4* xr = (const float4*)(x + (size_t)row * DDIM);
    const float4* yr = (const float4*)(y + (size_t)j * DDIM);
    float s = 0.f;
#pragma unroll
    for (int u = 0; u < 4; ++u) {
      const float4 a = xr[lane + 64 * u];
      const float4 b = yr[lane + 64 * u];
      s += a.x * b.x + a.y * b.y + a.z * b.z + a.w * b.w;
    }
    for (int m = 32; m; m >>= 1) s += __shfl_down(s, m, 64);
    if (lane == 0) {
      const float l = MARGIN_F - pos[row] + s;
      accl += l > 0.f ? l : 0.f;
    }
  }
  __shared__ float ps[4];
  if (lane == 0) ps[wave] = accl;
  __syncthreads();
  if (t == 0) atomicAdd(out, (ps[0] + ps[1] + ps[2] + ps[3]) * (1.0f / (float)NROWS));
}

extern "C" void kernel_launch(void* const* d_in, const int* in_sizes, int n_in,
                              void* d_out, int out_size, void* d_ws, size_t ws_size,
                              hipStream_t stream) {
  const float* x = (const float*)d_in[0];
  const float* y = (const float*)d_in[1];
  float* out = (float*)d_out;

  // ws layout: keys 32 KB | pos 32 KB | xq 8 MB | yq 8 MB
  unsigned int* keys = (unsigned int*)d_ws;
  float* pos = (float*)((char*)d_ws + (size_t)NROWS * 4);
  unsigned char* xq = (unsigned char*)d_ws + (size_t)NROWS * 8;
  unsigned char* yq = xq + (size_t)NROWS * DDIM;

  prep_kernel<<<NROWS / 4, 256, 0, stream>>>(x, y, (unsigned int*)xq, (unsigned int*)yq,
                                             pos, keys, out);
  dim3 grid(NROWS / BM, NSTRIPES);
  mine_kernel<<<grid, 256, 0, stream>>>(xq, yq, pos, keys);
  final_kernel<<<NROWS / 8, 256, 0, stream>>>(x, y, pos, keys, out);
}